// Round 20
// baseline (193.897 us; speedup 1.0000x reference)
//
#include <hip/hip_runtime.h>
#include <hip/hip_bf16.h>

typedef __attribute__((ext_vector_type(8))) short short8v;
typedef __attribute__((ext_vector_type(4))) float f32x4;
typedef __attribute__((ext_vector_type(2))) float f32x2;

// ---------------- helpers ----------------
__device__ __forceinline__ float lrelu(float x) { return x > 0.f ? x : 0.2f * x; }
__device__ __forceinline__ ushort f2bf(float v) {
  __hip_bfloat16 b = __float2bfloat16(v);
  return *(ushort*)&b;
}
__device__ __forceinline__ float bf2f(ushort u) {
  return __uint_as_float(((unsigned)u) << 16);
}
__device__ __forceinline__ f32x2 unpk_lo_hi(unsigned u) {
  return (f32x2){__uint_as_float(u << 16), __uint_as_float(u & 0xFFFF0000u)};
}
__device__ __forceinline__ float cvtub0(unsigned u) {
  float f; asm("v_cvt_f32_ubyte0 %0, %1" : "=v"(f) : "v"(u)); return f;
}
__device__ __forceinline__ float cvtub1(unsigned u) {
  float f; asm("v_cvt_f32_ubyte1 %0, %1" : "=v"(f) : "v"(u)); return f;
}
__device__ __forceinline__ float cvtub2(unsigned u) {
  float f; asm("v_cvt_f32_ubyte2 %0, %1" : "=v"(f) : "v"(u)); return f;
}
__device__ __forceinline__ float cvtub3(unsigned u) {
  float f; asm("v_cvt_f32_ubyte3 %0, %1" : "=v"(f) : "v"(u)); return f;
}
__device__ __forceinline__ void gload16(const ushort* g, ushort* l) {
  __builtin_amdgcn_global_load_lds((const __attribute__((address_space(1))) void*)g,
                                   (__attribute__((address_space(3))) void*)l, 16, 0, 0);
}

// ---------------- prep: pack_x (vec4) | pack_w ----------------
__global__ __launch_bounds__(256) void prep_kernel(const float* __restrict__ x,
    const float* __restrict__ W1, const float* __restrict__ W2,
    ushort* __restrict__ A1, ushort* __restrict__ B1t, ushort* __restrict__ B2t,
    int N, int Mpad, int PX) {
  int b = blockIdx.x, t = threadIdx.x;
  if (b < PX) {                       // pack x -> A1 bf16 [Mpad][256], 4 elems/thread
    int idx = (b * 256 + t) * 4;
    int row = idx >> 8, c = idx & 255;
    float4 v = (row < N) ? *(const float4*)&x[idx] : make_float4(0.f, 0.f, 0.f, 0.f);
    *(ushort4*)&A1[(size_t)row * 256 + c] =
        make_ushort4(f2bf(v.x), f2bf(v.y), f2bf(v.z), f2bf(v.w));
  } else {                            // pack W1/W2 -> Bt [NN][512] hi|lo
    int idx = (b - PX) * 256 + t;
    if (idx < 256 * 256) {
      int k = idx >> 8, col = idx & 255;
      float v = W1[idx];
      ushort hi = f2bf(v), lo = f2bf(v - bf2f(hi));
      size_t bb = (size_t)col * 512;
      B1t[bb + k] = hi;
      B1t[bb + 256 + k] = lo;
    } else if (idx < 256 * 256 + 256 * 64) {
      int j = idx - 256 * 256;
      int k = j >> 6, col = j & 63;
      float v = W2[j];
      ushort hi = f2bf(v), lo = f2bf(v - bf2f(hi));
      size_t bb = (size_t)col * 512;
      B2t[bb + k] = hi;
      B2t[bb + 256 + k] = lo;
    }
  }
}

// ---------------- two-level bucket sort (LDS atomics only) ----------------
// Pass A: partition edges by hi byte of dst into bufA ((dst<<16)|src).
// Pass B: per hi-bucket (contiguous), per-node counts via lo byte -> offsets +
// scatter ushort src_sorted. No global atomics; neighbor order arbitrary (OK).
static constexpr int RCH = 2048;   // edges per pass-A block

__global__ __launch_bounds__(256) void histA_kernel(const int* __restrict__ dst,
    int* __restrict__ histmat, int E, int Etot, int NBA) {
  __shared__ int h[256];
  int t = threadIdx.x, b = blockIdx.x;
  h[t] = 0;
  __syncthreads();
  int s0 = b * RCH, s1 = min(s0 + RCH, Etot);
  for (int e = s0 + t; e < s1; e += 256) {
    int d = (e < E) ? dst[e] : (e - E);
    atomicAdd(&h[d >> 8], 1);
  }
  __syncthreads();
  histmat[t * NBA + b] = h[t];       // bin-major for linear scan
}

__global__ __launch_bounds__(256) void scatterA_kernel(const int* __restrict__ src,
    const int* __restrict__ dst, const int* __restrict__ histscan,
    unsigned* __restrict__ bufA, int E, int Etot, int NBA) {
  __shared__ int cur[256];
  int t = threadIdx.x, b = blockIdx.x;
  cur[t] = histscan[t * NBA + b];
  __syncthreads();
  int s0 = b * RCH, s1 = min(s0 + RCH, Etot);
  for (int e = s0 + t; e < s1; e += 256) {
    int s = (e < E) ? src[e] : (e - E);
    int d = (e < E) ? dst[e] : (e - E);
    int pos = atomicAdd(&cur[d >> 8], 1);
    bufA[pos] = ((unsigned)d << 16) | (unsigned)s;
  }
}

__global__ __launch_bounds__(256) void passB_kernel(const unsigned* __restrict__ bufA,
    const int* __restrict__ histscan, ushort* __restrict__ src_sorted,
    int* __restrict__ offsets, int N, int Etot, int NBA, int NHB) {
  __shared__ int hist[256], cur[256], wsum[4];
  int t = threadIdx.x, hb = blockIdx.x;
  int base = histscan[(size_t)hb * NBA];
  int bend = (hb + 1 < NHB) ? histscan[(size_t)(hb + 1) * NBA] : Etot;
  hist[t] = 0;
  __syncthreads();
  for (int i = base + t; i < bend; i += 256)
    atomicAdd(&hist[(bufA[i] >> 16) & 255], 1);
  __syncthreads();
  int lane = t & 63, w = t >> 6;
  int v = hist[t];
  int x = v;
#pragma unroll
  for (int off = 1; off < 64; off <<= 1) {
    int y = __shfl_up(x, off, 64);
    if (lane >= off) x += y;
  }
  if (lane == 63) wsum[w] = x;
  __syncthreads();
  int wpre = 0;
  for (int ww = 0; ww < w; ++ww) wpre += wsum[ww];
  int ex = wpre + x - v;               // exclusive prefix over 256 lo-bins
  cur[t] = base + ex;
  int d = hb * 256 + t;
  if (d < N) offsets[d] = base + ex;
  __syncthreads();
  for (int i = base + t; i < bend; i += 256) {
    unsigned k = bufA[i];
    int pos = atomicAdd(&cur[(k >> 16) & 255], 1);
    src_sorted[pos] = (ushort)(k & 0xFFFFu);
  }
  if (hb == 0 && t == 0) offsets[N] = Etot;
}

// ---------------- MFMA GEMM with fused epilogues ----------------
// A: [Mpad][KAT] bf16, Bt: [NN][KT] bf16. KT=512, KAT=256 (k-fold: lo(W) half
// re-reads A). EPI=1: int8 quantized output (h1q[row][4f+h], hs[row][h] scale),
// requires NF==4 (wave owns one head). EPI=0: plain bf16 [M][NN].
template<int BN, int NF, int EPI, int KT, int KAT>
__global__ __launch_bounds__(256) void gemm_mfma(
    const ushort* __restrict__ A, const ushort* __restrict__ Bt,
    const float* __restrict__ avs, const float* __restrict__ avd,
    void* __restrict__ Hb, float* __restrict__ hs,
    float* __restrict__ os, float* __restrict__ od, int M, int NN) {
  constexpr int BM = 128, BK = 64;
  __shared__ ushort As[BM * BK];
  __shared__ ushort Bs[BN * BK];
  const int t = threadIdx.x, l = t & 63, w = t >> 6;
  const int l15 = l & 15, l4 = l >> 4;
  const int m0 = blockIdx.y * BM, n0 = blockIdx.x * BN;
  const int wr = w >> 1, wc = w & 1;
  f32x4 acc[4][NF];
#pragma unroll
  for (int m = 0; m < 4; ++m)
#pragma unroll
    for (int n = 0; n < NF; ++n) acc[m][n] = (f32x4){0.f, 0.f, 0.f, 0.f};

  for (int kk = 0; kk < KT; kk += BK) {
    const int ka = (kk < KAT) ? kk : kk - KAT;
    __syncthreads();
#pragma unroll
    for (int i = 0; i < 4; ++i) {
      int q = w * 4 + i;
      int c = q * 64 + l;
      int row = c >> 3, k8 = c & 7;
      int k8s = k8 ^ (row & 7);
      gload16(&A[(size_t)(m0 + row) * KAT + ka + k8s * 8], &As[q * 512]);
    }
    constexpr int BCHW = (BN * 8 / 64) / 4;
#pragma unroll
    for (int i = 0; i < BCHW; ++i) {
      int q = w * BCHW + i;
      int c = q * 64 + l;
      int col = c >> 3, k8 = c & 7;
      int k8s = k8 ^ (col & 7);
      gload16(&Bt[(size_t)(n0 + col) * KT + kk + k8s * 8], &Bs[q * 512]);
    }
    __syncthreads();
#pragma unroll
    for (int ks = 0; ks < 2; ++ks) {
      int kb = ks * 4 + l4;
      short8v af[4], bfr[NF];
#pragma unroll
      for (int m = 0; m < 4; ++m) {
        int row = wr * 64 + m * 16 + l15;
        af[m] = *(const short8v*)&As[row * 64 + (kb ^ (row & 7)) * 8];
      }
#pragma unroll
      for (int n = 0; n < NF; ++n) {
        int col = wc * (NF * 16) + n * 16 + l15;
        bfr[n] = *(const short8v*)&Bs[col * 64 + (kb ^ (col & 7)) * 8];
      }
#pragma unroll
      for (int m = 0; m < 4; ++m)
#pragma unroll
        for (int n = 0; n < NF; ++n)
          acc[m][n] = __builtin_amdgcn_mfma_f32_16x16x32_bf16(af[m], bfr[n], acc[m][n], 0, 0, 0);
    }
  }
  // ---- epilogue: output copy ----
  if (EPI == 1) {   // int8 per-(row,head)-scale quantized, interleaved [4f+h]
    unsigned char* hq = (unsigned char*)Hb;
    const int head = (n0 + wc * 64) >> 6;
#pragma unroll
    for (int m = 0; m < 4; ++m) {
#pragma unroll
      for (int r = 0; r < 4; ++r) {
        int row = m0 + wr * 64 + m * 16 + l4 * 4 + r;
        float s = 0.f;
#pragma unroll
        for (int n = 0; n < NF; ++n) s = fmaxf(s, fabsf(acc[m][n][r]));
#pragma unroll
        for (int off = 1; off < 16; off <<= 1) s = fmaxf(s, __shfl_xor(s, off, 64));
        float inv = s > 0.f ? 127.f / s : 0.f;
        if (row < M) {
          unsigned char* rp = hq + (size_t)row * 256;
#pragma unroll
          for (int n = 0; n < NF; ++n) {
            int f = n * 16 + l15;
            int qv = (int)rintf(acc[m][n][r] * inv) + 128;
            rp[4 * f + head] = (unsigned char)qv;
          }
          if (l15 == 0) hs[(size_t)row * 4 + head] = s * (1.f / 127.f);
        }
      }
    }
  } else {          // plain bf16 [M][NN]
    ushort* hb = (ushort*)Hb;
#pragma unroll
    for (int m = 0; m < 4; ++m) {
      int rbase = m0 + wr * 64 + m * 16 + l4 * 4;
#pragma unroll
      for (int n = 0; n < NF; ++n) {
        int gcol = n0 + wc * (NF * 16) + n * 16 + l15;
#pragma unroll
        for (int r = 0; r < 4; ++r) {
          int row = rbase + r;
          if (row < M) hb[(size_t)row * NN + gcol] = f2bf(acc[m][n][r]);
        }
      }
    }
  }
  // ---- epilogue: attention dots ----
  float cs[NF], cd[NF];
#pragma unroll
  for (int n = 0; n < NF; ++n) {
    int gc = n0 + wc * (NF * 16) + n * 16 + l15;
    cs[n] = avs[gc];
    cd[n] = avd[gc];
  }
  const int H = NN >> 6;
  const int head = (n0 + wc * (NF * 16)) >> 6;
#pragma unroll
  for (int m = 0; m < 4; ++m) {
#pragma unroll
    for (int r = 0; r < 4; ++r) {
      float ps = 0.f, pd = 0.f;
#pragma unroll
      for (int n = 0; n < NF; ++n) { ps += acc[m][n][r] * cs[n]; pd += acc[m][n][r] * cd[n]; }
#pragma unroll
      for (int off = 1; off < 16; off <<= 1) {
        ps += __shfl_xor(ps, off, 64);
        pd += __shfl_xor(pd, off, 64);
      }
      if (l15 == 0) {
        int row = m0 + wr * 64 + m * 16 + l4 * 4 + r;
        if (row < M) {
          if (NF == 4) {
            os[(size_t)row * H + head] = ps;
            od[(size_t)row * H + head] = pd;
          } else {
            atomicAdd(&os[row], ps);
            atomicAdd(&od[row], pd);
          }
        }
      }
    }
  }
}

// ---------------- hierarchical scan (3 coalesced phases) ----------------
static constexpr int SCB = 2048;

__global__ __launch_bounds__(256) void scan1_kernel(const int* __restrict__ counts,
    int* __restrict__ offsets, int* __restrict__ bsums, int n) {
  __shared__ int wsum[4];
  int t = threadIdx.x, lane = t & 63, w = t >> 6;
  int base = blockIdx.x * SCB + t * 8;
  int c[8];
  if (base + 7 < n) {
    int4 v0 = *(const int4*)&counts[base];
    int4 v1 = *(const int4*)&counts[base + 4];
    c[0] = v0.x; c[1] = v0.y; c[2] = v0.z; c[3] = v0.w;
    c[4] = v1.x; c[5] = v1.y; c[6] = v1.z; c[7] = v1.w;
  } else {
#pragma unroll
    for (int j = 0; j < 8; ++j) c[j] = (base + j < n) ? counts[base + j] : 0;
  }
  int ts = 0;
#pragma unroll
  for (int j = 0; j < 8; ++j) ts += c[j];
  int x = ts;
#pragma unroll
  for (int off = 1; off < 64; off <<= 1) {
    int y = __shfl_up(x, off, 64);
    if (lane >= off) x += y;
  }
  if (lane == 63) wsum[w] = x;
  __syncthreads();
  int wpre = 0;
  for (int ww = 0; ww < w; ++ww) wpre += wsum[ww];
  int ex = wpre + x - ts;
  int o[8];
#pragma unroll
  for (int j = 0; j < 8; ++j) { o[j] = ex; ex += c[j]; }
  if (base + 7 < n) {
    *(int4*)&offsets[base] = make_int4(o[0], o[1], o[2], o[3]);
    *(int4*)&offsets[base + 4] = make_int4(o[4], o[5], o[6], o[7]);
  } else {
#pragma unroll
    for (int j = 0; j < 8; ++j) if (base + j < n) offsets[base + j] = o[j];
  }
  if (t == 255) bsums[blockIdx.x] = wpre + x;
}

__global__ __launch_bounds__(256) void scan2_kernel(const int* __restrict__ bsums,
    int* __restrict__ bbase, int nb) {
  __shared__ int wsum[4];
  int t = threadIdx.x, lane = t & 63, w = t >> 6;
  int v = (t < nb) ? bsums[t] : 0;
  int x = v;
#pragma unroll
  for (int off = 1; off < 64; off <<= 1) {
    int y = __shfl_up(x, off, 64);
    if (lane >= off) x += y;
  }
  if (lane == 63) wsum[w] = x;
  __syncthreads();
  int wpre = 0;
  for (int ww = 0; ww < w; ++ww) wpre += wsum[ww];
  if (t < nb) bbase[t] = wpre + x - v;
}

__global__ __launch_bounds__(256) void scan3_kernel(int* __restrict__ offsets,
    const int* __restrict__ bbase, int n, int total) {
  int t = threadIdx.x;
  int bb = bbase[blockIdx.x];
  int base = blockIdx.x * SCB + t * 8;
  if (base + 7 < n) {
    int4 v0 = *(const int4*)&offsets[base];
    int4 v1 = *(const int4*)&offsets[base + 4];
    v0.x += bb; v0.y += bb; v0.z += bb; v0.w += bb;
    v1.x += bb; v1.y += bb; v1.z += bb; v1.w += bb;
    *(int4*)&offsets[base] = v0;
    *(int4*)&offsets[base + 4] = v1;
  } else {
#pragma unroll
    for (int j = 0; j < 8; ++j)
      if (base + j < n) offsets[base + j] += bb;
  }
  if (blockIdx.x == 0 && t == 0) offsets[n] = total;
}

// ---------------- aggregation layer 1 (int8 gather, 8-deep MLP) ---------------
// h1q: [N][256] uint8, byte 4f+h = head h, feat f (biased by 128). hs: [N][4]
// per-head scales (s/127). Staged LDS weight w = p * scale; acc = Σw*u - 128*Σw.
__global__ __launch_bounds__(256) void agg1_kernel(const unsigned char* __restrict__ h1q,
    const float* __restrict__ hs, const float* __restrict__ as1,
    const float* __restrict__ ad1, const int* __restrict__ offsets,
    const ushort* __restrict__ src_sorted, const float* __restrict__ b1,
    ushort* __restrict__ A2, int N, int Mpad) {
  __shared__ float4 pl[4][64];
  __shared__ alignas(16) unsigned sl[4][64];
  int wv = threadIdx.x >> 6;
  int wid = (blockIdx.x << 2) + wv;
  int lane = threadIdx.x & 63;
  if (wid >= Mpad) return;
  size_t ab = (size_t)wid * 256;
  if (wid >= N) {
#pragma unroll
    for (int i = 0; i < 4; ++i) A2[ab + i * 64 + lane] = 0;
    return;
  }
  float4 ah = *(const float4*)&ad1[(size_t)wid * 4];
  int st = offsets[wid], en = offsets[wid + 1];
  float acc0 = 0.f, acc1 = 0.f, acc2 = 0.f, acc3 = 0.f;
  float ds0 = 0.f, ds1 = 0.f, ds2 = 0.f, ds3 = 0.f;
  float ws0 = 0.f, ws1 = 0.f, ws2 = 0.f, ws3 = 0.f;
  const unsigned lo4 = (unsigned)lane * 4;
  for (int c = st; c < en; c += 64) {
    int mye = c + lane;
    float4 w4 = make_float4(0.f, 0.f, 0.f, 0.f);
    unsigned soff = 0;
    if (mye < en) {
      int smy = (int)src_sorted[mye];
      soff = ((unsigned)smy << 8);
      float4 a4 = *(const float4*)&as1[(size_t)smy * 4];
      float4 sc4 = *(const float4*)&hs[(size_t)smy * 4];
      float p0 = __expf(lrelu(a4.x + ah.x));
      float p1 = __expf(lrelu(a4.y + ah.y));
      float p2 = __expf(lrelu(a4.z + ah.z));
      float p3 = __expf(lrelu(a4.w + ah.w));
      ds0 += p0; ds1 += p1; ds2 += p2; ds3 += p3;
      w4 = make_float4(p0 * sc4.x, p1 * sc4.y, p2 * sc4.z, p3 * sc4.w);
      ws0 += w4.x; ws1 += w4.y; ws2 += w4.z; ws3 += w4.w;
    }
    pl[wv][lane] = w4;
    sl[wv][lane] = soff;
    int cnt = min(64, en - c);
    int e = 0;
    for (; e + 8 <= cnt; e += 8) {
      uint4 sa = *(const uint4*)&sl[wv][e];       // uniform addr -> broadcast
      uint4 sb = *(const uint4*)&sl[wv][e + 4];
      // issue all 8 independent gathers before any math
      unsigned u0 = *(const unsigned*)(h1q + (sa.x + lo4));
      unsigned u1 = *(const unsigned*)(h1q + (sa.y + lo4));
      unsigned u2 = *(const unsigned*)(h1q + (sa.z + lo4));
      unsigned u3 = *(const unsigned*)(h1q + (sa.w + lo4));
      unsigned u4 = *(const unsigned*)(h1q + (sb.x + lo4));
      unsigned u5 = *(const unsigned*)(h1q + (sb.y + lo4));
      unsigned u6 = *(const unsigned*)(h1q + (sb.z + lo4));
      unsigned u7 = *(const unsigned*)(h1q + (sb.w + lo4));
      float4 w0 = pl[wv][e + 0];
      float4 w1 = pl[wv][e + 1];
      float4 w2 = pl[wv][e + 2];
      float4 w3 = pl[wv][e + 3];
      float4 w4e = pl[wv][e + 4];
      float4 w5 = pl[wv][e + 5];
      float4 w6 = pl[wv][e + 6];
      float4 w7 = pl[wv][e + 7];
      acc0 = fmaf(w0.x, cvtub0(u0), acc0); acc1 = fmaf(w0.y, cvtub1(u0), acc1);
      acc2 = fmaf(w0.z, cvtub2(u0), acc2); acc3 = fmaf(w0.w, cvtub3(u0), acc3);
      acc0 = fmaf(w1.x, cvtub0(u1), acc0); acc1 = fmaf(w1.y, cvtub1(u1), acc1);
      acc2 = fmaf(w1.z, cvtub2(u1), acc2); acc3 = fmaf(w1.w, cvtub3(u1), acc3);
      acc0 = fmaf(w2.x, cvtub0(u2), acc0); acc1 = fmaf(w2.y, cvtub1(u2), acc1);
      acc2 = fmaf(w2.z, cvtub2(u2), acc2); acc3 = fmaf(w2.w, cvtub3(u2), acc3);
      acc0 = fmaf(w3.x, cvtub0(u3), acc0); acc1 = fmaf(w3.y, cvtub1(u3), acc1);
      acc2 = fmaf(w3.z, cvtub2(u3), acc2); acc3 = fmaf(w3.w, cvtub3(u3), acc3);
      acc0 = fmaf(w4e.x, cvtub0(u4), acc0); acc1 = fmaf(w4e.y, cvtub1(u4), acc1);
      acc2 = fmaf(w4e.z, cvtub2(u4), acc2); acc3 = fmaf(w4e.w, cvtub3(u4), acc3);
      acc0 = fmaf(w5.x, cvtub0(u5), acc0); acc1 = fmaf(w5.y, cvtub1(u5), acc1);
      acc2 = fmaf(w5.z, cvtub2(u5), acc2); acc3 = fmaf(w5.w, cvtub3(u5), acc3);
      acc0 = fmaf(w6.x, cvtub0(u6), acc0); acc1 = fmaf(w6.y, cvtub1(u6), acc1);
      acc2 = fmaf(w6.z, cvtub2(u6), acc2); acc3 = fmaf(w6.w, cvtub3(u6), acc3);
      acc0 = fmaf(w7.x, cvtub0(u7), acc0); acc1 = fmaf(w7.y, cvtub1(u7), acc1);
      acc2 = fmaf(w7.z, cvtub2(u7), acc2); acc3 = fmaf(w7.w, cvtub3(u7), acc3);
    }
    for (; e < cnt; ++e) {
      unsigned sb = sl[wv][e];
      float4 wq = pl[wv][e];
      unsigned u = *(const unsigned*)(h1q + (sb + lo4));
      acc0 = fmaf(wq.x, cvtub0(u), acc0); acc1 = fmaf(wq.y, cvtub1(u), acc1);
      acc2 = fmaf(wq.z, cvtub2(u), acc2); acc3 = fmaf(wq.w, cvtub3(u), acc3);
    }
  }
#pragma unroll
  for (int off = 32; off > 0; off >>= 1) {
    ds0 += __shfl_xor(ds0, off, 64);
    ds1 += __shfl_xor(ds1, off, 64);
    ds2 += __shfl_xor(ds2, off, 64);
    ds3 += __shfl_xor(ds3, off, 64);
    ws0 += __shfl_xor(ws0, off, 64);
    ws1 += __shfl_xor(ws1, off, 64);
    ws2 += __shfl_xor(ws2, off, 64);
    ws3 += __shfl_xor(ws3, off, 64);
  }
  float v[4];
  v[0] = fmaxf((acc0 - 128.f * ws0) / (ds0 + 1e-16f) + b1[lane], 0.f);
  v[1] = fmaxf((acc1 - 128.f * ws1) / (ds1 + 1e-16f) + b1[64 + lane], 0.f);
  v[2] = fmaxf((acc2 - 128.f * ws2) / (ds2 + 1e-16f) + b1[128 + lane], 0.f);
  v[3] = fmaxf((acc3 - 128.f * ws3) / (ds3 + 1e-16f) + b1[192 + lane], 0.f);
#pragma unroll
  for (int h = 0; h < 4; ++h) A2[ab + h * 64 + lane] = f2bf(v[h]);
}

// ---------------- aggregation layer 2 (4 edges per wave-step) -----------------
__global__ __launch_bounds__(256) void agg2_kernel(const ushort* __restrict__ h2b,
    const float* __restrict__ as2, const float* __restrict__ ad2,
    const int* __restrict__ offsets, const ushort* __restrict__ src_sorted,
    const float* __restrict__ b2, float* __restrict__ out, int N) {
  __shared__ float pl[4][64];
  __shared__ alignas(16) int sl[4][64];
  int wv = threadIdx.x >> 6;
  int wid = (blockIdx.x << 2) + wv;
  int lane = threadIdx.x & 63;
  if (wid >= N) return;
  const int qtr = lane >> 4;
  const int fl = lane & 15;
  float ah = ad2[wid];
  int st = offsets[wid], en = offsets[wid + 1];
  f32x2 a01 = (f32x2){0.f, 0.f}, a23 = (f32x2){0.f, 0.f};
  float ds = 0.f;
  for (int c = st; c < en; c += 64) {
    int mye = c + lane;
    float p = 0.f;
    int smy = 0;
    if (mye < en) {
      smy = (int)src_sorted[mye];
      p = __expf(lrelu(as2[smy] + ah));
    }
    ds += p;
    pl[wv][lane] = p;
    sl[wv][lane] = smy;
    int cnt = min(64, en - c);
    for (int e = 0; e < cnt; e += 4) {
      int e2 = e + qtr;
      int row = sl[wv][e2];
      float q = pl[wv][e2];
      uint2 u = *(const uint2*)&h2b[(size_t)row * 64 + fl * 4];
      a01 += (f32x2){q, q} * unpk_lo_hi(u.x);
      a23 += (f32x2){q, q} * unpk_lo_hi(u.y);
    }
  }
#pragma unroll
  for (int off = 32; off > 0; off >>= 1) ds += __shfl_xor(ds, off, 64);
#pragma unroll
  for (int off = 16; off <= 32; off <<= 1) {
    a01.x += __shfl_xor(a01.x, off, 64);
    a01.y += __shfl_xor(a01.y, off, 64);
    a23.x += __shfl_xor(a23.x, off, 64);
    a23.y += __shfl_xor(a23.y, off, 64);
  }
  if (lane < 16) {
    float inv = 1.f / (ds + 1e-16f);
    float4 bb = *(const float4*)&b2[fl * 4];
    float4 o;
    o.x = a01.x * inv + bb.x;
    o.y = a01.y * inv + bb.y;
    o.z = a23.x * inv + bb.z;
    o.w = a23.y * inv + bb.w;
    *(float4*)&out[(size_t)wid * 64 + fl * 4] = o;
  }
}

// ---------------- launch ----------------
extern "C" void kernel_launch(void* const* d_in, const int* in_sizes, int n_in,
                              void* d_out, int out_size, void* d_ws, size_t ws_size,
                              hipStream_t stream) {
  const float* x      = (const float*)d_in[0];
  const int*   ei     = (const int*)d_in[1];
  const float* W1     = (const float*)d_in[2];
  const float* a_src1 = (const float*)d_in[3];
  const float* a_dst1 = (const float*)d_in[4];
  const float* b1     = (const float*)d_in[5];
  const float* W2     = (const float*)d_in[6];
  const float* a_src2 = (const float*)d_in[7];
  const float* a_dst2 = (const float*)d_in[8];
  const float* b2     = (const float*)d_in[9];
  float* out = (float*)d_out;

  const int IN = 256, HD = 256, D2 = 64;
  const int N = in_sizes[0] / IN;
  const int E = in_sizes[1] / 2;
  const int Etot = E + N;
  const int Mpad = ((N + 127) / 128) * 128;
  const int* srcp = ei;
  const int* dstp = ei + E;
  const int NBA = (Etot + RCH - 1) / RCH;    // pass-A blocks
  const int NHB = (N + 255) / 256;           // hi-byte buckets
  const int NH  = NBA * 256;                 // histmat entries

  uintptr_t base = (uintptr_t)d_ws;
  auto alloc_bytes = [&](size_t nbytes) -> void* {
    void* p = (void*)base;
    base += (nbytes + 255) & ~(size_t)255;
    return p;
  };
  ushort* A1        = (ushort*)alloc_bytes((size_t)Mpad * 256 * 2);
  ushort* A2        = (ushort*)alloc_bytes((size_t)Mpad * 256 * 2);
  unsigned char* h1q = (unsigned char*)alloc_bytes((size_t)N * 256);
  float* hs         = (float*)alloc_bytes((size_t)N * 4 * 4);
  ushort* h2b       = (ushort*)alloc_bytes((size_t)N * D2 * 2);
  ushort* B1t       = (ushort*)alloc_bytes((size_t)HD * 512 * 2);
  ushort* B2t       = (ushort*)alloc_bytes((size_t)D2 * 512 * 2);
  float* as1        = (float*)alloc_bytes((size_t)N * 4 * 4);
  float* ad1        = (float*)alloc_bytes((size_t)N * 4 * 4);
  // zero-init region start
  float* as2        = (float*)alloc_bytes((size_t)N * 4);
  float* ad2        = (float*)alloc_bytes((size_t)N * 4);
  uintptr_t zero_end = base;
  // zero-init region end
  int* offsets      = (int*)alloc_bytes((size_t)(N + 1) * 4);
  ushort* src_sorted = (ushort*)alloc_bytes((size_t)Etot * 2);
  unsigned* bufA    = (unsigned*)alloc_bytes((size_t)Etot * 4);
  int* histmat      = (int*)alloc_bytes((size_t)(NH + 1) * 4);
  int* histscan     = (int*)alloc_bytes((size_t)(NH + 1) * 4);
  int* bsums        = (int*)alloc_bytes(256 * 4);
  int* bbase        = (int*)alloc_bytes(256 * 4);

  hipMemsetAsync((void*)as2, 0, zero_end - (uintptr_t)as2, stream);

  const int nwb  = (N + 3) / 4;
  const int nwbp = (Mpad + 3) / 4;
  const int nsbA = (NH + SCB - 1) / SCB;
  const int PX = Mpad / 4;                           // pack_x blocks (4 elems/thr)
  const int PW = (256 * 256 + 256 * 64) / 256;       // pack_w blocks

  prep_kernel<<<PX + PW, 256, 0, stream>>>(x, W1, W2, A1, B1t, B2t, N, Mpad, PX);
  // CSR build: two-level 8-bit bucket sort (LDS atomics only)
  histA_kernel<<<NBA, 256, 0, stream>>>(dstp, histmat, E, Etot, NBA);
  scan1_kernel<<<nsbA, 256, 0, stream>>>(histmat, histscan, bsums, NH);
  scan2_kernel<<<1, 256, 0, stream>>>(bsums, bbase, nsbA);
  scan3_kernel<<<nsbA, 256, 0, stream>>>(histscan, bbase, NH, Etot);
  scatterA_kernel<<<NBA, 256, 0, stream>>>(srcp, dstp, histscan, bufA, E, Etot, NBA);
  passB_kernel<<<NHB, 256, 0, stream>>>(bufA, histscan, src_sorted, offsets,
                                        N, Etot, NBA, NHB);
  // layer 1
  gemm_mfma<128, 4, 1, 512, 256><<<dim3(HD / 128, Mpad / 128), 256, 0, stream>>>(
      A1, B1t, a_src1, a_dst1, (void*)h1q, hs, as1, ad1, N, HD);
  agg1_kernel<<<nwbp, 256, 0, stream>>>(h1q, hs, as1, ad1, offsets, src_sorted, b1, A2, N, Mpad);
  // layer 2
  gemm_mfma<64, 2, 0, 512, 256><<<dim3(D2 / 64, Mpad / 128), 256, 0, stream>>>(
      A2, B2t, a_src2, a_dst2, (void*)h2b, nullptr, as2, ad2, N, D2);
  agg2_kernel<<<nwb, 256, 0, stream>>>(h2b, as2, ad2, offsets, src_sorted, b2, out, N);
}

// Round 21
// 187.558 us; speedup vs baseline: 1.0338x; 1.0338x over previous
//
#include <hip/hip_runtime.h>
#include <hip/hip_bf16.h>

typedef __attribute__((ext_vector_type(8))) short short8v;
typedef __attribute__((ext_vector_type(4))) float f32x4;
typedef __attribute__((ext_vector_type(2))) float f32x2;

// ---------------- helpers ----------------
__device__ __forceinline__ float lrelu(float x) { return x > 0.f ? x : 0.2f * x; }
__device__ __forceinline__ ushort f2bf(float v) {
  __hip_bfloat16 b = __float2bfloat16(v);
  return *(ushort*)&b;
}
__device__ __forceinline__ float bf2f(ushort u) {
  return __uint_as_float(((unsigned)u) << 16);
}
__device__ __forceinline__ f32x2 unpk_lo_hi(unsigned u) {
  return (f32x2){__uint_as_float(u << 16), __uint_as_float(u & 0xFFFF0000u)};
}
__device__ __forceinline__ float cvtub0(unsigned u) {
  float f; asm("v_cvt_f32_ubyte0 %0, %1" : "=v"(f) : "v"(u)); return f;
}
__device__ __forceinline__ float cvtub1(unsigned u) {
  float f; asm("v_cvt_f32_ubyte1 %0, %1" : "=v"(f) : "v"(u)); return f;
}
__device__ __forceinline__ float cvtub2(unsigned u) {
  float f; asm("v_cvt_f32_ubyte2 %0, %1" : "=v"(f) : "v"(u)); return f;
}
__device__ __forceinline__ float cvtub3(unsigned u) {
  float f; asm("v_cvt_f32_ubyte3 %0, %1" : "=v"(f) : "v"(u)); return f;
}
__device__ __forceinline__ void gload16(const ushort* g, ushort* l) {
  __builtin_amdgcn_global_load_lds((const __attribute__((address_space(1))) void*)g,
                                   (__attribute__((address_space(3))) void*)l, 16, 0, 0);
}

// ---------------- prep: pack_x (vec4) | pack_w ----------------
__global__ __launch_bounds__(256) void prep_kernel(const float* __restrict__ x,
    const float* __restrict__ W1, const float* __restrict__ W2,
    ushort* __restrict__ A1, ushort* __restrict__ B1t, ushort* __restrict__ B2t,
    int N, int Mpad, int PX) {
  int b = blockIdx.x, t = threadIdx.x;
  if (b < PX) {                       // pack x -> A1 bf16 [Mpad][256], 4 elems/thread
    int idx = (b * 256 + t) * 4;
    int row = idx >> 8, c = idx & 255;
    float4 v = (row < N) ? *(const float4*)&x[idx] : make_float4(0.f, 0.f, 0.f, 0.f);
    *(ushort4*)&A1[(size_t)row * 256 + c] =
        make_ushort4(f2bf(v.x), f2bf(v.y), f2bf(v.z), f2bf(v.w));
  } else {                            // pack W1/W2 -> Bt [NN][512] hi|lo
    int idx = (b - PX) * 256 + t;
    if (idx < 256 * 256) {
      int k = idx >> 8, col = idx & 255;
      float v = W1[idx];
      ushort hi = f2bf(v), lo = f2bf(v - bf2f(hi));
      size_t bb = (size_t)col * 512;
      B1t[bb + k] = hi;
      B1t[bb + 256 + k] = lo;
    } else if (idx < 256 * 256 + 256 * 64) {
      int j = idx - 256 * 256;
      int k = j >> 6, col = j & 63;
      float v = W2[j];
      ushort hi = f2bf(v), lo = f2bf(v - bf2f(hi));
      size_t bb = (size_t)col * 512;
      B2t[bb + k] = hi;
      B2t[bb + 256 + k] = lo;
    }
  }
}

// ---------------- two-level bucket sort (LDS atomics only) ----------------
// Pass A: partition edges by hi byte of dst into bufA ((dst<<16)|src).
// Pass B: per hi-bucket (contiguous), per-node counts via lo byte -> offsets +
// scatter ushort src_sorted. No global atomics; neighbor order arbitrary (OK).
static constexpr int RCH = 2048;   // edges per pass-A block

__global__ __launch_bounds__(256) void histA_kernel(const int* __restrict__ dst,
    int* __restrict__ histmat, int E, int Etot, int NBA) {
  __shared__ int h[256];
  int t = threadIdx.x, b = blockIdx.x;
  h[t] = 0;
  __syncthreads();
  int s0 = b * RCH, s1 = min(s0 + RCH, Etot);
  for (int e = s0 + t; e < s1; e += 256) {
    int d = (e < E) ? dst[e] : (e - E);
    atomicAdd(&h[d >> 8], 1);
  }
  __syncthreads();
  histmat[t * NBA + b] = h[t];       // bin-major for linear scan
}

__global__ __launch_bounds__(256) void scatterA_kernel(const int* __restrict__ src,
    const int* __restrict__ dst, const int* __restrict__ histscan,
    unsigned* __restrict__ bufA, int E, int Etot, int NBA) {
  __shared__ int cur[256];
  int t = threadIdx.x, b = blockIdx.x;
  cur[t] = histscan[t * NBA + b];
  __syncthreads();
  int s0 = b * RCH, s1 = min(s0 + RCH, Etot);
  for (int e = s0 + t; e < s1; e += 256) {
    int s = (e < E) ? src[e] : (e - E);
    int d = (e < E) ? dst[e] : (e - E);
    int pos = atomicAdd(&cur[d >> 8], 1);
    bufA[pos] = ((unsigned)d << 16) | (unsigned)s;
  }
}

__global__ __launch_bounds__(256) void passB_kernel(const unsigned* __restrict__ bufA,
    const int* __restrict__ histscan, ushort* __restrict__ src_sorted,
    int* __restrict__ offsets, int N, int Etot, int NBA, int NHB) {
  __shared__ int hist[256], cur[256], wsum[4];
  int t = threadIdx.x, hb = blockIdx.x;
  int base = histscan[(size_t)hb * NBA];
  int bend = (hb + 1 < NHB) ? histscan[(size_t)(hb + 1) * NBA] : Etot;
  hist[t] = 0;
  __syncthreads();
  for (int i = base + t; i < bend; i += 256)
    atomicAdd(&hist[(bufA[i] >> 16) & 255], 1);
  __syncthreads();
  int lane = t & 63, w = t >> 6;
  int v = hist[t];
  int x = v;
#pragma unroll
  for (int off = 1; off < 64; off <<= 1) {
    int y = __shfl_up(x, off, 64);
    if (lane >= off) x += y;
  }
  if (lane == 63) wsum[w] = x;
  __syncthreads();
  int wpre = 0;
  for (int ww = 0; ww < w; ++ww) wpre += wsum[ww];
  int ex = wpre + x - v;               // exclusive prefix over 256 lo-bins
  cur[t] = base + ex;
  int d = hb * 256 + t;
  if (d < N) offsets[d] = base + ex;
  __syncthreads();
  for (int i = base + t; i < bend; i += 256) {
    unsigned k = bufA[i];
    int pos = atomicAdd(&cur[(k >> 16) & 255], 1);
    src_sorted[pos] = (ushort)(k & 0xFFFFu);
  }
  if (hb == 0 && t == 0) offsets[N] = Etot;
}

// ---------------- MFMA GEMM with fused epilogues ----------------
// A: [Mpad][KAT] bf16, Bt: [NN][KT] bf16. KT=512, KAT=256 (k-fold: lo(W) half
// re-reads A). EPI=1: int8 quantized output (h1q[row][4f+h], hs[row][h] scale),
// requires NF==4 (wave owns one head). EPI=0: plain bf16 [M][NN].
template<int BN, int NF, int EPI, int KT, int KAT>
__global__ __launch_bounds__(256) void gemm_mfma(
    const ushort* __restrict__ A, const ushort* __restrict__ Bt,
    const float* __restrict__ avs, const float* __restrict__ avd,
    void* __restrict__ Hb, float* __restrict__ hs,
    float* __restrict__ os, float* __restrict__ od, int M, int NN) {
  constexpr int BM = 128, BK = 64;
  __shared__ ushort As[BM * BK];
  __shared__ ushort Bs[BN * BK];
  const int t = threadIdx.x, l = t & 63, w = t >> 6;
  const int l15 = l & 15, l4 = l >> 4;
  const int m0 = blockIdx.y * BM, n0 = blockIdx.x * BN;
  const int wr = w >> 1, wc = w & 1;
  f32x4 acc[4][NF];
#pragma unroll
  for (int m = 0; m < 4; ++m)
#pragma unroll
    for (int n = 0; n < NF; ++n) acc[m][n] = (f32x4){0.f, 0.f, 0.f, 0.f};

  for (int kk = 0; kk < KT; kk += BK) {
    const int ka = (kk < KAT) ? kk : kk - KAT;
    __syncthreads();
#pragma unroll
    for (int i = 0; i < 4; ++i) {
      int q = w * 4 + i;
      int c = q * 64 + l;
      int row = c >> 3, k8 = c & 7;
      int k8s = k8 ^ (row & 7);
      gload16(&A[(size_t)(m0 + row) * KAT + ka + k8s * 8], &As[q * 512]);
    }
    constexpr int BCHW = (BN * 8 / 64) / 4;
#pragma unroll
    for (int i = 0; i < BCHW; ++i) {
      int q = w * BCHW + i;
      int c = q * 64 + l;
      int col = c >> 3, k8 = c & 7;
      int k8s = k8 ^ (col & 7);
      gload16(&Bt[(size_t)(n0 + col) * KT + kk + k8s * 8], &Bs[q * 512]);
    }
    __syncthreads();
#pragma unroll
    for (int ks = 0; ks < 2; ++ks) {
      int kb = ks * 4 + l4;
      short8v af[4], bfr[NF];
#pragma unroll
      for (int m = 0; m < 4; ++m) {
        int row = wr * 64 + m * 16 + l15;
        af[m] = *(const short8v*)&As[row * 64 + (kb ^ (row & 7)) * 8];
      }
#pragma unroll
      for (int n = 0; n < NF; ++n) {
        int col = wc * (NF * 16) + n * 16 + l15;
        bfr[n] = *(const short8v*)&Bs[col * 64 + (kb ^ (col & 7)) * 8];
      }
#pragma unroll
      for (int m = 0; m < 4; ++m)
#pragma unroll
        for (int n = 0; n < NF; ++n)
          acc[m][n] = __builtin_amdgcn_mfma_f32_16x16x32_bf16(af[m], bfr[n], acc[m][n], 0, 0, 0);
    }
  }
  // ---- epilogue: output copy ----
  if (EPI == 1) {   // int8 per-(row,head)-scale quantized, interleaved [4f+h]
    unsigned char* hq = (unsigned char*)Hb;
    const int head = (n0 + wc * 64) >> 6;
#pragma unroll
    for (int m = 0; m < 4; ++m) {
#pragma unroll
      for (int r = 0; r < 4; ++r) {
        int row = m0 + wr * 64 + m * 16 + l4 * 4 + r;
        float s = 0.f;
#pragma unroll
        for (int n = 0; n < NF; ++n) s = fmaxf(s, fabsf(acc[m][n][r]));
#pragma unroll
        for (int off = 1; off < 16; off <<= 1) s = fmaxf(s, __shfl_xor(s, off, 64));
        float inv = s > 0.f ? 127.f / s : 0.f;
        if (row < M) {
          unsigned char* rp = hq + (size_t)row * 256;
#pragma unroll
          for (int n = 0; n < NF; ++n) {
            int f = n * 16 + l15;
            int qv = (int)rintf(acc[m][n][r] * inv) + 128;
            rp[4 * f + head] = (unsigned char)qv;
          }
          if (l15 == 0) hs[(size_t)row * 4 + head] = s * (1.f / 127.f);
        }
      }
    }
  } else {          // plain bf16 [M][NN]
    ushort* hb = (ushort*)Hb;
#pragma unroll
    for (int m = 0; m < 4; ++m) {
      int rbase = m0 + wr * 64 + m * 16 + l4 * 4;
#pragma unroll
      for (int n = 0; n < NF; ++n) {
        int gcol = n0 + wc * (NF * 16) + n * 16 + l15;
#pragma unroll
        for (int r = 0; r < 4; ++r) {
          int row = rbase + r;
          if (row < M) hb[(size_t)row * NN + gcol] = f2bf(acc[m][n][r]);
        }
      }
    }
  }
  // ---- epilogue: attention dots ----
  float cs[NF], cd[NF];
#pragma unroll
  for (int n = 0; n < NF; ++n) {
    int gc = n0 + wc * (NF * 16) + n * 16 + l15;
    cs[n] = avs[gc];
    cd[n] = avd[gc];
  }
  const int H = NN >> 6;
  const int head = (n0 + wc * (NF * 16)) >> 6;
#pragma unroll
  for (int m = 0; m < 4; ++m) {
#pragma unroll
    for (int r = 0; r < 4; ++r) {
      float ps = 0.f, pd = 0.f;
#pragma unroll
      for (int n = 0; n < NF; ++n) { ps += acc[m][n][r] * cs[n]; pd += acc[m][n][r] * cd[n]; }
#pragma unroll
      for (int off = 1; off < 16; off <<= 1) {
        ps += __shfl_xor(ps, off, 64);
        pd += __shfl_xor(pd, off, 64);
      }
      if (l15 == 0) {
        int row = m0 + wr * 64 + m * 16 + l4 * 4 + r;
        if (row < M) {
          if (NF == 4) {
            os[(size_t)row * H + head] = ps;
            od[(size_t)row * H + head] = pd;
          } else {
            atomicAdd(&os[row], ps);
            atomicAdd(&od[row], pd);
          }
        }
      }
    }
  }
}

// ---------------- hierarchical scan (3 coalesced phases) ----------------
static constexpr int SCB = 2048;

__global__ __launch_bounds__(256) void scan1_kernel(const int* __restrict__ counts,
    int* __restrict__ offsets, int* __restrict__ bsums, int n) {
  __shared__ int wsum[4];
  int t = threadIdx.x, lane = t & 63, w = t >> 6;
  int base = blockIdx.x * SCB + t * 8;
  int c[8];
  if (base + 7 < n) {
    int4 v0 = *(const int4*)&counts[base];
    int4 v1 = *(const int4*)&counts[base + 4];
    c[0] = v0.x; c[1] = v0.y; c[2] = v0.z; c[3] = v0.w;
    c[4] = v1.x; c[5] = v1.y; c[6] = v1.z; c[7] = v1.w;
  } else {
#pragma unroll
    for (int j = 0; j < 8; ++j) c[j] = (base + j < n) ? counts[base + j] : 0;
  }
  int ts = 0;
#pragma unroll
  for (int j = 0; j < 8; ++j) ts += c[j];
  int x = ts;
#pragma unroll
  for (int off = 1; off < 64; off <<= 1) {
    int y = __shfl_up(x, off, 64);
    if (lane >= off) x += y;
  }
  if (lane == 63) wsum[w] = x;
  __syncthreads();
  int wpre = 0;
  for (int ww = 0; ww < w; ++ww) wpre += wsum[ww];
  int ex = wpre + x - ts;
  int o[8];
#pragma unroll
  for (int j = 0; j < 8; ++j) { o[j] = ex; ex += c[j]; }
  if (base + 7 < n) {
    *(int4*)&offsets[base] = make_int4(o[0], o[1], o[2], o[3]);
    *(int4*)&offsets[base + 4] = make_int4(o[4], o[5], o[6], o[7]);
  } else {
#pragma unroll
    for (int j = 0; j < 8; ++j) if (base + j < n) offsets[base + j] = o[j];
  }
  if (t == 255) bsums[blockIdx.x] = wpre + x;
}

__global__ __launch_bounds__(256) void scan2_kernel(const int* __restrict__ bsums,
    int* __restrict__ bbase, int nb) {
  __shared__ int wsum[4];
  int t = threadIdx.x, lane = t & 63, w = t >> 6;
  int v = (t < nb) ? bsums[t] : 0;
  int x = v;
#pragma unroll
  for (int off = 1; off < 64; off <<= 1) {
    int y = __shfl_up(x, off, 64);
    if (lane >= off) x += y;
  }
  if (lane == 63) wsum[w] = x;
  __syncthreads();
  int wpre = 0;
  for (int ww = 0; ww < w; ++ww) wpre += wsum[ww];
  if (t < nb) bbase[t] = wpre + x - v;
}

__global__ __launch_bounds__(256) void scan3_kernel(int* __restrict__ offsets,
    const int* __restrict__ bbase, int n, int total) {
  int t = threadIdx.x;
  int bb = bbase[blockIdx.x];
  int base = blockIdx.x * SCB + t * 8;
  if (base + 7 < n) {
    int4 v0 = *(const int4*)&offsets[base];
    int4 v1 = *(const int4*)&offsets[base + 4];
    v0.x += bb; v0.y += bb; v0.z += bb; v0.w += bb;
    v1.x += bb; v1.y += bb; v1.z += bb; v1.w += bb;
    *(int4*)&offsets[base] = v0;
    *(int4*)&offsets[base + 4] = v1;
  } else {
#pragma unroll
    for (int j = 0; j < 8; ++j)
      if (base + j < n) offsets[base + j] += bb;
  }
  if (blockIdx.x == 0 && t == 0) offsets[n] = total;
}

// ---------------- aggregation layer 1 (int8 gather, 4-deep MLP) ---------------
// h1q: [N][256] uint8, byte 4f+h = head h, feat f (biased by 128). hs: [N][4]
// per-head scales (s/127). Staged LDS weight w = p * scale; acc = Σw*u - 128*Σw.
__global__ __launch_bounds__(256) void agg1_kernel(const unsigned char* __restrict__ h1q,
    const float* __restrict__ hs, const float* __restrict__ as1,
    const float* __restrict__ ad1, const int* __restrict__ offsets,
    const ushort* __restrict__ src_sorted, const float* __restrict__ b1,
    ushort* __restrict__ A2, int N, int Mpad) {
  __shared__ float4 pl[4][64];
  __shared__ alignas(16) unsigned sl[4][64];
  int wv = threadIdx.x >> 6;
  int wid = (blockIdx.x << 2) + wv;
  int lane = threadIdx.x & 63;
  if (wid >= Mpad) return;
  size_t ab = (size_t)wid * 256;
  if (wid >= N) {
#pragma unroll
    for (int i = 0; i < 4; ++i) A2[ab + i * 64 + lane] = 0;
    return;
  }
  float4 ah = *(const float4*)&ad1[(size_t)wid * 4];
  int st = offsets[wid], en = offsets[wid + 1];
  float acc0 = 0.f, acc1 = 0.f, acc2 = 0.f, acc3 = 0.f;
  float ds0 = 0.f, ds1 = 0.f, ds2 = 0.f, ds3 = 0.f;
  float ws0 = 0.f, ws1 = 0.f, ws2 = 0.f, ws3 = 0.f;
  const unsigned lo4 = (unsigned)lane * 4;
  for (int c = st; c < en; c += 64) {
    int mye = c + lane;
    float4 w4 = make_float4(0.f, 0.f, 0.f, 0.f);
    unsigned soff = 0;
    if (mye < en) {
      int smy = (int)src_sorted[mye];
      soff = ((unsigned)smy << 8);
      float4 a4 = *(const float4*)&as1[(size_t)smy * 4];
      float4 sc4 = *(const float4*)&hs[(size_t)smy * 4];
      float p0 = __expf(lrelu(a4.x + ah.x));
      float p1 = __expf(lrelu(a4.y + ah.y));
      float p2 = __expf(lrelu(a4.z + ah.z));
      float p3 = __expf(lrelu(a4.w + ah.w));
      ds0 += p0; ds1 += p1; ds2 += p2; ds3 += p3;
      w4 = make_float4(p0 * sc4.x, p1 * sc4.y, p2 * sc4.z, p3 * sc4.w);
      ws0 += w4.x; ws1 += w4.y; ws2 += w4.z; ws3 += w4.w;
    }
    pl[wv][lane] = w4;
    sl[wv][lane] = soff;
    int cnt = min(64, en - c);
    int e = 0;
    for (; e + 4 <= cnt; e += 4) {
      uint4 s4 = *(const uint4*)&sl[wv][e];   // uniform addr -> broadcast
      float4 w0 = pl[wv][e + 0];
      float4 w1 = pl[wv][e + 1];
      float4 w2 = pl[wv][e + 2];
      float4 w3 = pl[wv][e + 3];
      unsigned u0 = *(const unsigned*)(h1q + (s4.x + lo4));
      unsigned u1 = *(const unsigned*)(h1q + (s4.y + lo4));
      unsigned u2 = *(const unsigned*)(h1q + (s4.z + lo4));
      unsigned u3 = *(const unsigned*)(h1q + (s4.w + lo4));
      acc0 = fmaf(w0.x, cvtub0(u0), acc0); acc1 = fmaf(w0.y, cvtub1(u0), acc1);
      acc2 = fmaf(w0.z, cvtub2(u0), acc2); acc3 = fmaf(w0.w, cvtub3(u0), acc3);
      acc0 = fmaf(w1.x, cvtub0(u1), acc0); acc1 = fmaf(w1.y, cvtub1(u1), acc1);
      acc2 = fmaf(w1.z, cvtub2(u1), acc2); acc3 = fmaf(w1.w, cvtub3(u1), acc3);
      acc0 = fmaf(w2.x, cvtub0(u2), acc0); acc1 = fmaf(w2.y, cvtub1(u2), acc1);
      acc2 = fmaf(w2.z, cvtub2(u2), acc2); acc3 = fmaf(w2.w, cvtub3(u2), acc3);
      acc0 = fmaf(w3.x, cvtub0(u3), acc0); acc1 = fmaf(w3.y, cvtub1(u3), acc1);
      acc2 = fmaf(w3.z, cvtub2(u3), acc2); acc3 = fmaf(w3.w, cvtub3(u3), acc3);
    }
    for (; e < cnt; ++e) {
      unsigned sb = sl[wv][e];
      float4 w4e = pl[wv][e];
      unsigned u = *(const unsigned*)(h1q + (sb + lo4));
      acc0 = fmaf(w4e.x, cvtub0(u), acc0); acc1 = fmaf(w4e.y, cvtub1(u), acc1);
      acc2 = fmaf(w4e.z, cvtub2(u), acc2); acc3 = fmaf(w4e.w, cvtub3(u), acc3);
    }
  }
#pragma unroll
  for (int off = 32; off > 0; off >>= 1) {
    ds0 += __shfl_xor(ds0, off, 64);
    ds1 += __shfl_xor(ds1, off, 64);
    ds2 += __shfl_xor(ds2, off, 64);
    ds3 += __shfl_xor(ds3, off, 64);
    ws0 += __shfl_xor(ws0, off, 64);
    ws1 += __shfl_xor(ws1, off, 64);
    ws2 += __shfl_xor(ws2, off, 64);
    ws3 += __shfl_xor(ws3, off, 64);
  }
  float v[4];
  v[0] = fmaxf((acc0 - 128.f * ws0) / (ds0 + 1e-16f) + b1[lane], 0.f);
  v[1] = fmaxf((acc1 - 128.f * ws1) / (ds1 + 1e-16f) + b1[64 + lane], 0.f);
  v[2] = fmaxf((acc2 - 128.f * ws2) / (ds2 + 1e-16f) + b1[128 + lane], 0.f);
  v[3] = fmaxf((acc3 - 128.f * ws3) / (ds3 + 1e-16f) + b1[192 + lane], 0.f);
#pragma unroll
  for (int h = 0; h < 4; ++h) A2[ab + h * 64 + lane] = f2bf(v[h]);
}

// ---------------- aggregation layer 2 (4 edges per wave-step) -----------------
__global__ __launch_bounds__(256) void agg2_kernel(const ushort* __restrict__ h2b,
    const float* __restrict__ as2, const float* __restrict__ ad2,
    const int* __restrict__ offsets, const ushort* __restrict__ src_sorted,
    const float* __restrict__ b2, float* __restrict__ out, int N) {
  __shared__ float pl[4][64];
  __shared__ alignas(16) int sl[4][64];
  int wv = threadIdx.x >> 6;
  int wid = (blockIdx.x << 2) + wv;
  int lane = threadIdx.x & 63;
  if (wid >= N) return;
  const int qtr = lane >> 4;
  const int fl = lane & 15;
  float ah = ad2[wid];
  int st = offsets[wid], en = offsets[wid + 1];
  f32x2 a01 = (f32x2){0.f, 0.f}, a23 = (f32x2){0.f, 0.f};
  float ds = 0.f;
  for (int c = st; c < en; c += 64) {
    int mye = c + lane;
    float p = 0.f;
    int smy = 0;
    if (mye < en) {
      smy = (int)src_sorted[mye];
      p = __expf(lrelu(as2[smy] + ah));
    }
    ds += p;
    pl[wv][lane] = p;
    sl[wv][lane] = smy;
    int cnt = min(64, en - c);
    for (int e = 0; e < cnt; e += 4) {
      int e2 = e + qtr;
      int row = sl[wv][e2];
      float q = pl[wv][e2];
      uint2 u = *(const uint2*)&h2b[(size_t)row * 64 + fl * 4];
      a01 += (f32x2){q, q} * unpk_lo_hi(u.x);
      a23 += (f32x2){q, q} * unpk_lo_hi(u.y);
    }
  }
#pragma unroll
  for (int off = 32; off > 0; off >>= 1) ds += __shfl_xor(ds, off, 64);
#pragma unroll
  for (int off = 16; off <= 32; off <<= 1) {
    a01.x += __shfl_xor(a01.x, off, 64);
    a01.y += __shfl_xor(a01.y, off, 64);
    a23.x += __shfl_xor(a23.x, off, 64);
    a23.y += __shfl_xor(a23.y, off, 64);
  }
  if (lane < 16) {
    float inv = 1.f / (ds + 1e-16f);
    float4 bb = *(const float4*)&b2[fl * 4];
    float4 o;
    o.x = a01.x * inv + bb.x;
    o.y = a01.y * inv + bb.y;
    o.z = a23.x * inv + bb.z;
    o.w = a23.y * inv + bb.w;
    *(float4*)&out[(size_t)wid * 64 + fl * 4] = o;
  }
}

// ---------------- launch ----------------
extern "C" void kernel_launch(void* const* d_in, const int* in_sizes, int n_in,
                              void* d_out, int out_size, void* d_ws, size_t ws_size,
                              hipStream_t stream) {
  const float* x      = (const float*)d_in[0];
  const int*   ei     = (const int*)d_in[1];
  const float* W1     = (const float*)d_in[2];
  const float* a_src1 = (const float*)d_in[3];
  const float* a_dst1 = (const float*)d_in[4];
  const float* b1     = (const float*)d_in[5];
  const float* W2     = (const float*)d_in[6];
  const float* a_src2 = (const float*)d_in[7];
  const float* a_dst2 = (const float*)d_in[8];
  const float* b2     = (const float*)d_in[9];
  float* out = (float*)d_out;

  const int IN = 256, HD = 256, D2 = 64;
  const int N = in_sizes[0] / IN;
  const int E = in_sizes[1] / 2;
  const int Etot = E + N;
  const int Mpad = ((N + 127) / 128) * 128;
  const int* srcp = ei;
  const int* dstp = ei + E;
  const int NBA = (Etot + RCH - 1) / RCH;    // pass-A blocks
  const int NHB = (N + 255) / 256;           // hi-byte buckets
  const int NH  = NBA * 256;                 // histmat entries

  uintptr_t base = (uintptr_t)d_ws;
  auto alloc_bytes = [&](size_t nbytes) -> void* {
    void* p = (void*)base;
    base += (nbytes + 255) & ~(size_t)255;
    return p;
  };
  ushort* A1        = (ushort*)alloc_bytes((size_t)Mpad * 256 * 2);
  ushort* A2        = (ushort*)alloc_bytes((size_t)Mpad * 256 * 2);
  unsigned char* h1q = (unsigned char*)alloc_bytes((size_t)N * 256);
  float* hs         = (float*)alloc_bytes((size_t)N * 4 * 4);
  ushort* h2b       = (ushort*)alloc_bytes((size_t)N * D2 * 2);
  ushort* B1t       = (ushort*)alloc_bytes((size_t)HD * 512 * 2);
  ushort* B2t       = (ushort*)alloc_bytes((size_t)D2 * 512 * 2);
  float* as1        = (float*)alloc_bytes((size_t)N * 4 * 4);
  float* ad1        = (float*)alloc_bytes((size_t)N * 4 * 4);
  // zero-init region start
  float* as2        = (float*)alloc_bytes((size_t)N * 4);
  float* ad2        = (float*)alloc_bytes((size_t)N * 4);
  uintptr_t zero_end = base;
  // zero-init region end
  int* offsets      = (int*)alloc_bytes((size_t)(N + 1) * 4);
  ushort* src_sorted = (ushort*)alloc_bytes((size_t)Etot * 2);
  unsigned* bufA    = (unsigned*)alloc_bytes((size_t)Etot * 4);
  int* histmat      = (int*)alloc_bytes((size_t)(NH + 1) * 4);
  int* histscan     = (int*)alloc_bytes((size_t)(NH + 1) * 4);
  int* bsums        = (int*)alloc_bytes(256 * 4);
  int* bbase        = (int*)alloc_bytes(256 * 4);

  hipMemsetAsync((void*)as2, 0, zero_end - (uintptr_t)as2, stream);

  const int nwb  = (N + 3) / 4;
  const int nwbp = (Mpad + 3) / 4;
  const int nsbA = (NH + SCB - 1) / SCB;
  const int PX = Mpad / 4;                           // pack_x blocks (4 elems/thr)
  const int PW = (256 * 256 + 256 * 64) / 256;       // pack_w blocks

  prep_kernel<<<PX + PW, 256, 0, stream>>>(x, W1, W2, A1, B1t, B2t, N, Mpad, PX);
  // CSR build: two-level 8-bit bucket sort (LDS atomics only)
  histA_kernel<<<NBA, 256, 0, stream>>>(dstp, histmat, E, Etot, NBA);
  scan1_kernel<<<nsbA, 256, 0, stream>>>(histmat, histscan, bsums, NH);
  scan2_kernel<<<1, 256, 0, stream>>>(bsums, bbase, nsbA);
  scan3_kernel<<<nsbA, 256, 0, stream>>>(histscan, bbase, NH, Etot);
  scatterA_kernel<<<NBA, 256, 0, stream>>>(srcp, dstp, histscan, bufA, E, Etot, NBA);
  passB_kernel<<<NHB, 256, 0, stream>>>(bufA, histscan, src_sorted, offsets,
                                        N, Etot, NBA, NHB);
  // layer 1
  gemm_mfma<128, 4, 1, 512, 256><<<dim3(HD / 128, Mpad / 128), 256, 0, stream>>>(
      A1, B1t, a_src1, a_dst1, (void*)h1q, hs, as1, ad1, N, HD);
  agg1_kernel<<<nwbp, 256, 0, stream>>>(h1q, hs, as1, ad1, offsets, src_sorted, b1, A2, N, Mpad);
  // layer 2
  gemm_mfma<64, 2, 0, 512, 256><<<dim3(D2 / 64, Mpad / 128), 256, 0, stream>>>(
      A2, B2t, a_src2, a_dst2, (void*)h2b, nullptr, as2, ad2, N, D2);
  agg2_kernel<<<nwb, 256, 0, stream>>>(h2b, as2, ad2, offsets, src_sorted, b2, out, N);
}